// Round 2
// baseline (335.395 us; speedup 1.0000x reference)
//
#include <hip/hip_runtime.h>

// Adaptive avg pool 2D: in (32,50,50,768) f32 NHWC -> out (32,7,7,768).
// in=50, out=7: start_i = (i*50)/7 = {0,7,14,21,28,35,42}, window = 8 always.
// Separable: pass 1 pools W into d_ws (32,50,7,768), pass 2 pools H.

#define N_   32
#define HIN  50
#define WIN  50
#define C_   768
#define HOUT 7
#define WOUT 7
#define CG   (C_ / 4)                     // 192 float4 groups per pixel

#define P1_TOTAL (N_ * HIN * WOUT * CG)   // 2,150,400 threads
#define P2_TOTAL (N_ * HOUT * WOUT * CG)  //   301,056 threads

// Pass 1: out_ws[n][h][wo][cg] = sum_{dw<8} in[n][h][ws+dw][cg]
__global__ __launch_bounds__(256) void pool_w_kernel(
    const float4* __restrict__ in, float4* __restrict__ ws_out) {
    int idx = blockIdx.x * blockDim.x + threadIdx.x;
    if (idx >= P1_TOTAL) return;

    int cg = idx % CG;
    int t  = idx / CG;
    int wo = t % WOUT; t /= WOUT;
    int h  = t % HIN;
    int n  = t / HIN;

    int w0 = wo * 7;  // (wo*50)/7 = wo*7 + floor(wo/7)... check: wo in [0,7), (wo*50)/7 = {0,7,14,21,28,35,42} = wo*7 + wo/7? no: 50/7=7.14 -> floor(wo*50/7): wo=1 ->7, wo=6 ->42. == 7*wo. yes.

    const float4* base = in + ((size_t)((n * HIN + h) * WIN + w0)) * CG + cg;

    float4 v0 = base[0 * CG];
    float4 v1 = base[1 * CG];
    float4 v2 = base[2 * CG];
    float4 v3 = base[3 * CG];
    float4 v4 = base[4 * CG];
    float4 v5 = base[5 * CG];
    float4 v6 = base[6 * CG];
    float4 v7 = base[7 * CG];

    float4 acc;
    acc.x = (v0.x + v1.x) + (v2.x + v3.x) + ((v4.x + v5.x) + (v6.x + v7.x));
    acc.y = (v0.y + v1.y) + (v2.y + v3.y) + ((v4.y + v5.y) + (v6.y + v7.y));
    acc.z = (v0.z + v1.z) + (v2.z + v3.z) + ((v4.z + v5.z) + (v6.z + v7.z));
    acc.w = (v0.w + v1.w) + (v2.w + v3.w) + ((v4.w + v5.w) + (v6.w + v7.w));

    ws_out[idx] = acc;
}

// Pass 2: out[n][ho][wo][cg] = (1/64) * sum_{dh<8} ws[n][hs+dh][wo][cg]
__global__ __launch_bounds__(256) void pool_h_kernel(
    const float4* __restrict__ ws_in, float4* __restrict__ out) {
    int idx = blockIdx.x * blockDim.x + threadIdx.x;
    if (idx >= P2_TOTAL) return;

    int cg = idx % CG;
    int t  = idx / CG;
    int wo = t % WOUT; t /= WOUT;
    int ho = t % HOUT;
    int n  = t / HOUT;

    int h0 = ho * 7;  // same boundary math as W

    const float4* base = ws_in + ((size_t)((n * HIN + h0) * WOUT + wo)) * CG + cg;
    const int rs = WOUT * CG;  // 1344 float4 per h row

    float4 v0 = base[0 * rs];
    float4 v1 = base[1 * rs];
    float4 v2 = base[2 * rs];
    float4 v3 = base[3 * rs];
    float4 v4 = base[4 * rs];
    float4 v5 = base[5 * rs];
    float4 v6 = base[6 * rs];
    float4 v7 = base[7 * rs];

    const float s = 1.0f / 64.0f;
    float4 acc;
    acc.x = s * ((v0.x + v1.x) + (v2.x + v3.x) + ((v4.x + v5.x) + (v6.x + v7.x)));
    acc.y = s * ((v0.y + v1.y) + (v2.y + v3.y) + ((v4.y + v5.y) + (v6.y + v7.y)));
    acc.z = s * ((v0.z + v1.z) + (v2.z + v3.z) + ((v4.z + v5.z) + (v6.z + v7.z)));
    acc.w = s * ((v0.w + v1.w) + (v2.w + v3.w) + ((v4.w + v5.w) + (v6.w + v7.w)));

    out[idx] = acc;
}

extern "C" void kernel_launch(void* const* d_in, const int* in_sizes, int n_in,
                              void* d_out, int out_size, void* d_ws, size_t ws_size,
                              hipStream_t stream) {
    const float4* in  = (const float4*)d_in[0];
    float4*       out = (float4*)d_out;
    float4*       ws  = (float4*)d_ws;   // needs 32*50*7*768*4 = 34.4 MB

    pool_w_kernel<<<(P1_TOTAL + 255) / 256, 256, 0, stream>>>(in, ws);
    pool_h_kernel<<<(P2_TOTAL + 255) / 256, 256, 0, stream>>>(ws, out);
}

// Round 3
// 329.466 us; speedup vs baseline: 1.0180x; 1.0180x over previous
//
#include <hip/hip_runtime.h>

// Adaptive avg pool 2D: in (32,50,50,768) f32 NHWC -> out (32,7,7,768).
// in=50 -> out=7: start = wo*7 (== floor(wo*50/7)), window = 8 for every index.
// Fused single kernel: block = (n, ho). 384 threads = 2 row-halves x 192
// channel-groups (float4). Each thread pools 4 rows x 7 windows; the two
// row-halves reduce through LDS. Input rows are read once per block
// (W-overlap duplicates hit L1); total HBM ~275 MB read + 4.8 MB write.

#define N_   32
#define HIN  50
#define WIN  50
#define C_   768
#define HOUT 7
#define WOUT 7
#define CG   (C_ / 4)   // 192 float4 per pixel

__global__ __launch_bounds__(384) void adaptive_pool_fused(
    const float4* __restrict__ in, float4* __restrict__ out) {
    __shared__ float4 lds[WOUT][CG];   // 7*192*16 = 21504 B

    const int bid = blockIdx.x;        // 0..223
    const int n  = bid / HOUT;
    const int ho = bid % HOUT;
    const int h0 = ho * 7;

    const int tid = threadIdx.x;       // 0..383
    const int rh  = tid / CG;          // 0 or 1 (wave-uniform: waves 0-2 vs 3-5)
    const int cg  = tid % CG;

    float4 acc[WOUT];
    #pragma unroll
    for (int wo = 0; wo < WOUT; ++wo)
        acc[wo] = make_float4(0.f, 0.f, 0.f, 0.f);

    // rows h0 + rh*4 + 0..3
    const int hbase = h0 + rh * 4;
    #pragma unroll
    for (int dh = 0; dh < 4; ++dh) {
        const float4* rp = in + ((size_t)((n * HIN + (hbase + dh)) * WIN)) * CG + cg;
        #pragma unroll
        for (int wo = 0; wo < WOUT; ++wo) {
            const float4* wp = rp + (size_t)(wo * 7) * CG;
            float4 v0 = wp[0 * CG];
            float4 v1 = wp[1 * CG];
            float4 v2 = wp[2 * CG];
            float4 v3 = wp[3 * CG];
            float4 v4 = wp[4 * CG];
            float4 v5 = wp[5 * CG];
            float4 v6 = wp[6 * CG];
            float4 v7 = wp[7 * CG];
            acc[wo].x += ((v0.x + v1.x) + (v2.x + v3.x)) + ((v4.x + v5.x) + (v6.x + v7.x));
            acc[wo].y += ((v0.y + v1.y) + (v2.y + v3.y)) + ((v4.y + v5.y) + (v6.y + v7.y));
            acc[wo].z += ((v0.z + v1.z) + (v2.z + v3.z)) + ((v4.z + v5.z) + (v6.z + v7.z));
            acc[wo].w += ((v0.w + v1.w) + (v2.w + v3.w)) + ((v4.w + v5.w) + (v6.w + v7.w));
        }
    }

    // row-half 1 publishes its partial sums
    if (rh == 1) {
        #pragma unroll
        for (int wo = 0; wo < WOUT; ++wo)
            lds[wo][cg] = acc[wo];
    }
    __syncthreads();

    if (rh == 0) {
        const float s = 1.0f / 64.0f;
        float4* op = out + ((size_t)((n * HOUT + ho) * WOUT)) * CG + cg;
        #pragma unroll
        for (int wo = 0; wo < WOUT; ++wo) {
            float4 o = lds[wo][cg];
            o.x = s * (o.x + acc[wo].x);
            o.y = s * (o.y + acc[wo].y);
            o.z = s * (o.z + acc[wo].z);
            o.w = s * (o.w + acc[wo].w);
            op[(size_t)wo * CG] = o;
        }
    }
}

extern "C" void kernel_launch(void* const* d_in, const int* in_sizes, int n_in,
                              void* d_out, int out_size, void* d_ws, size_t ws_size,
                              hipStream_t stream) {
    const float4* in  = (const float4*)d_in[0];
    float4*       out = (float4*)d_out;
    adaptive_pool_fused<<<N_ * HOUT, 384, 0, stream>>>(in, out);
}